// Round 14
// baseline (791.313 us; speedup 1.0000x reference)
//
#include <hip/hip_runtime.h>
#include <hip/hip_bf16.h>

using u16 = unsigned short;
using u32 = unsigned int;

typedef __bf16 bf16x8 __attribute__((ext_vector_type(8)));
typedef float f32x4 __attribute__((ext_vector_type(4)));
typedef float f32x4v __attribute__((ext_vector_type(4)));
typedef unsigned short u16x8 __attribute__((ext_vector_type(8)));

constexpr int NT  = 8192;   // B*T tokens
constexpr int DIM = 1024;
constexpr int FF  = 4096;
constexpr int NE  = 8;      // experts

constexpr int BM = 128, BN = 128, BK = 128;   // BK=128: half the K-tiles, same stall each
constexpr int MAXMB = 136;              // max m-blocks: NT*2/BM + NE  (= 17*8)
constexpr int G1X = MAXMB * (FF / BN);  // 136*32 = 4352  (%8==0)
constexpr int G2X = MAXMB * (DIM / BN); // 136*8  = 1088  (%8==0)

__device__ inline u16 f2bf(float f) {
    u32 u = __float_as_uint(f);
    u32 r = (u + 0x7fffu + ((u >> 16) & 1u)) >> 16;
    return (u16)r;
}

// direct global->LDS, 16B per lane, wave-uniform LDS base + lane*16
__device__ inline void gload16(const void* g, void* l) {
    __builtin_amdgcn_global_load_lds(
        (const __attribute__((address_space(1))) void*)g,
        (__attribute__((address_space(3))) void*)l, 16, 0, 0);
}

// derive (e, m0, off, cnt) for m-block xm from counts[8] (8-step scalar scan)
__device__ inline bool derive_mb(const int* __restrict__ counts, int xm,
                                 int& e, int& m0, int& off, int& cnt) {
    int cum = 0, ofs = 0;
    e = -1;
#pragma unroll
    for (int ee = 0; ee < NE; ee++) {
        int c = counts[ee];
        int nb = (c + BM - 1) >> 7;
        if (e < 0) {
            if (xm < cum + nb) { e = ee; m0 = (xm - cum) * BM; cnt = c; off = ofs; }
            else ofs += c;
        }
        cum += nb;
    }
    return e >= 0;
}

// ---------------- router: logits -> top2 -> softmax weights (+ x -> bf16) ----------------
__global__ __launch_bounds__(256) void k_router(const float* __restrict__ x,
                                                const float* __restrict__ Wr,
                                                int* __restrict__ topi,
                                                float* __restrict__ topw,
                                                int* __restrict__ counts,
                                                u16* __restrict__ xbf) {
    int w = threadIdx.x >> 6, lane = threadIdx.x & 63;
    int t = blockIdx.x * 4 + w;
    const float* xt = x + (size_t)t * DIM;
    u16* xo = xbf + (size_t)t * DIM;
    float acc[NE];
#pragma unroll
    for (int e = 0; e < NE; e++) acc[e] = 0.f;
    for (int i = 0; i < DIM / 64; i++) {
        int d = i * 64 + lane;
        float xv = xt[d];
        xo[d] = f2bf(xv);                       // fused x -> bf16 (coalesced)
#pragma unroll
        for (int e = 0; e < NE; e++) acc[e] += xv * Wr[e * DIM + d];
    }
#pragma unroll
    for (int e = 0; e < NE; e++) {
#pragma unroll
        for (int off = 32; off >= 1; off >>= 1) acc[e] += __shfl_xor(acc[e], off, 64);
    }
    if (lane == 0) {
        int b0 = 0; float v0 = acc[0];
        for (int e = 1; e < NE; e++) if (acc[e] > v0) { v0 = acc[e]; b0 = e; }
        int b1 = -1; float v1 = -INFINITY;
        for (int e = 0; e < NE; e++) if (e != b0 && acc[e] > v1) { v1 = acc[e]; b1 = e; }
        float e1 = __expf(v1 - v0);
        float w0 = 1.f / (1.f + e1);
        topi[t * 2] = b0; topi[t * 2 + 1] = b1;
        topw[t * 2] = w0; topw[t * 2 + 1] = 1.f - w0;
        atomicAdd(&counts[b0], 1);
        atomicAdd(&counts[b1], 1);
    }
}

// ---------------- build per-expert row lists (ballot-aggregated atomics) ----------------
__global__ __launch_bounds__(256) void k_build(const int* __restrict__ topi,
                                               const float* __restrict__ topw,
                                               const int* __restrict__ counts,
                                               int* __restrict__ cur0,
                                               int* __restrict__ rows,
                                               float* __restrict__ roww) {
    int t = blockIdx.x * 256 + threadIdx.x;
    int lane = threadIdx.x & 63;
    int offsL[NE]; int s = 0;
#pragma unroll
    for (int e = 0; e < NE; e++) { offsL[e] = s; s += counts[e]; }
#pragma unroll
    for (int sl = 0; sl < 2; sl++) {
        int e = topi[t * 2 + sl];
#pragma unroll
        for (int ee = 0; ee < NE; ee++) {
            unsigned long long mask = __ballot(e == ee);
            if (e == ee) {
                int leader = __ffsll((long long)mask) - 1;
                int cntw = __popcll(mask);
                int base = 0;
                if (lane == leader) base = atomicAdd(&cur0[ee], cntw);
                base = __shfl(base, leader, 64);
                int rank = __popcll(mask & ((1ULL << lane) - 1ULL));
                int p = offsL[ee] + base + rank;
                rows[p] = t * 2 + sl;
                roww[p] = topw[t * 2 + sl];
            }
        }
    }
}

// ---------------- fused transpose+convert for W1 and W2 ----------------
__global__ __launch_bounds__(256) void k_tcvt2(const float* __restrict__ W1,
                                               const float* __restrict__ W2,
                                               u16* __restrict__ w1t,
                                               u16* __restrict__ w2t) {
    __shared__ float tile[64][65];
    int b = blockIdx.x;
    const float* pin; u16* pout; int R, C, cx, cy;
    if (b < 8192) {
        int e = b >> 10, r = b & 1023;
        cx = r & 63; cy = r >> 6;               // (FF/64)=64 x (DIM/64)=16
        R = DIM; C = FF;
        pin = W1 + (size_t)e * DIM * FF;
        pout = w1t + (size_t)e * DIM * FF;
    } else {
        int bb = b - 8192;
        int e = bb >> 10, r = bb & 1023;
        cx = r & 15; cy = r >> 4;               // (DIM/64)=16 x (FF/64)=64
        R = FF; C = DIM;
        pin = W2 + (size_t)e * DIM * FF;
        pout = w2t + (size_t)e * DIM * FF;
    }
    int c0 = cx * 64, r0 = cy * 64;
    int t = threadIdx.x;
    int lc = (t & 15) * 4, lr = t >> 4;
#pragma unroll
    for (int i = 0; i < 4; i++) {
        int r = lr + i * 16;
        f32x4v v = *reinterpret_cast<const f32x4v*>(&pin[(size_t)(r0 + r) * C + c0 + lc]);
        tile[r][lc] = v[0]; tile[r][lc + 1] = v[1];
        tile[r][lc + 2] = v[2]; tile[r][lc + 3] = v[3];
    }
    __syncthreads();
    int oc = (t & 7) * 8;
    int orow = t >> 3;
#pragma unroll
    for (int i = 0; i < 2; i++) {
        int cc = orow + i * 32;
        u16x8 o;
#pragma unroll
        for (int j = 0; j < 8; j++) o[j] = f2bf(tile[oc + j][cc]);
        *reinterpret_cast<u16x8*>(&pout[(size_t)(c0 + cc) * R + r0 + oc]) = o;
    }
}

// ======== single-buffer 128x128x128 GEMM machinery ========
// LDS swizzle (both-sides, BK=128): chunk c (16B): row=c>>4, slot t=c&15 holds
// global col-chunk g=t^(row&7) (XOR within 8-slot halves); frag read slot
// s=(kk*4+(lane>>4))^(row&7), kk 0..3. Row stride 256B == 0 mod 32 banks ->
// per-instruction bank pattern identical to the verified BK=64 case (0 conflicts).
// STAGE: 8 chunks A + 8 chunks B per thread. LDS 64 KB -> 2 blocks/CU (same as
// measured occupancy at BK=64, so no occupancy loss; m132's regression was the
// 128KB-dbuf 1-block case).

#define STAGE(kt) do { \
    _Pragma("unroll") for (int i_ = 0; i_ < 8; i_++) \
        gload16(aSrc[i_] + (kt) * BK, &Als[i_ * 2048 + ldsOff]); \
    _Pragma("unroll") for (int i_ = 0; i_ < 8; i_++) \
        gload16(bSrc[i_] + (kt) * BK, &Bls[i_ * 2048 + ldsOff]); \
} while (0)

#define COMPUTE() do { \
    _Pragma("unroll") for (int kk = 0; kk < 4; kk++) { \
        bf16x8 af[4], bfr[4]; \
        _Pragma("unroll") for (int mi = 0; mi < 4; mi++) { \
            int row = wr * 64 + mi * 16 + (lane & 15); \
            int s = (kk * 4 + (lane >> 4)) ^ (row & 7); \
            af[mi] = *reinterpret_cast<const bf16x8*>(&Als[row * BK + s * 8]); } \
        _Pragma("unroll") for (int nj = 0; nj < 4; nj++) { \
            int row = wc * 64 + nj * 16 + (lane & 15); \
            int s = (kk * 4 + (lane >> 4)) ^ (row & 7); \
            bfr[nj] = *reinterpret_cast<const bf16x8*>(&Bls[row * BK + s * 8]); } \
        _Pragma("unroll") for (int mi = 0; mi < 4; mi++) \
        _Pragma("unroll") for (int nj = 0; nj < 4; nj++) \
            acc[mi][nj] = __builtin_amdgcn_mfma_f32_16x16x32_bf16(af[mi], bfr[nj], acc[mi][nj], 0, 0, 0); \
    } \
} while (0)

// ---------------- GEMM1: H = gelu(x @ W1[e]) ----------------
__global__ __launch_bounds__(256, 2) void k_gemm1(const u16* __restrict__ xbf,
                                                  const u16* __restrict__ w1t, // [E][FF][DIM]
                                                  const int* __restrict__ rows,
                                                  const int* __restrict__ counts,
                                                  u16* __restrict__ H) {
    int l = ((int)blockIdx.x & 7) * (G1X >> 3) + ((int)blockIdx.x >> 3);
    // grouped-snake: groups of 8 token-panels (2 MB, L2-resident) sweep all 32
    // weight panels; weights stream once via L3 instead of 8x64 MB thrash.
    int gid = l >> 8;                 // l / 256  (17 groups)
    int xm = gid * 8 + ((l & 255) & 7);
    int yn = (l & 255) >> 3;
    int e, m0, off, cnt;
    if (!derive_mb(counts, xm, e, m0, off, cnt)) return;
    int n0 = yn * BN;

    __shared__ __align__(16) u16 Als[BM * BK];   // 32 KB
    __shared__ __align__(16) u16 Bls[BN * BK];   // 32 KB

    int tid = threadIdx.x;
    int lane = tid & 63, wid = tid >> 6;
    int wr = wid >> 1, wc = wid & 1;

    f32x4 acc[4][4];
#pragma unroll
    for (int i = 0; i < 4; i++)
#pragma unroll
        for (int j = 0; j < 4; j++) acc[i][j] = (f32x4)(0.f);

    const u16* aSrc[8];
    const u16* bSrc[8];
#pragma unroll
    for (int i = 0; i < 8; i++) {
        int c = i * 256 + tid;
        int row = c >> 4;                    // i*16 + (tid>>4)
        int g = (c & 15) ^ (row & 7);        // c&15 == tid&15; row&7 == (tid>>4)&7
        int lrow = m0 + row;
        int tok = (lrow < cnt) ? (rows[off + lrow] >> 1) : 0;
        aSrc[i] = xbf + (size_t)tok * DIM + g * 8;
        bSrc[i] = w1t + (size_t)e * FF * DIM + (size_t)(n0 + row) * DIM + g * 8;
    }
    int ldsOff = wid * 512;   // elems; + i*2048 per chunk

    constexpr int NKT = DIM / BK;  // 8
#pragma unroll 2
    for (int kt = 0; kt < NKT; ++kt) {
        STAGE(kt);
        __syncthreads();   // drains vmcnt; tile ready
        COMPUTE();
        __syncthreads();   // reads done; safe to restage
    }

    // epilogue: exact GELU -> bf16 H
#pragma unroll
    for (int mi = 0; mi < 4; mi++) {
#pragma unroll
        for (int r = 0; r < 4; r++) {
            int lrow = m0 + wr * 64 + mi * 16 + ((lane >> 4) << 2) + r;
            if (lrow >= cnt) continue;
            u16* hp = H + (size_t)(off + lrow) * FF + n0 + wc * 64;
#pragma unroll
            for (int nj = 0; nj < 4; nj++) {
                float v = acc[mi][nj][r];
                v = 0.5f * v * (1.f + erff(v * 0.70710678118f));
                hp[nj * 16 + (lane & 15)] = f2bf(v);
            }
        }
    }
}

// ---------------- GEMM2: out[token] += w * (H[row] @ W2[e]) ----------------
__global__ __launch_bounds__(256, 2) void k_gemm2(const u16* __restrict__ H,
                                                  const u16* __restrict__ w2t, // [E][DIM][FF]
                                                  const int* __restrict__ rows,
                                                  const float* __restrict__ roww,
                                                  const int* __restrict__ counts,
                                                  float* __restrict__ out) {
    int l = ((int)blockIdx.x & 7) * (G2X >> 3) + ((int)blockIdx.x >> 3);
    int xm = l >> 3, yn = l & 7;    // yn inner: H-panel L2-hot per XCD
    int e, m0, off, cnt;
    if (!derive_mb(counts, xm, e, m0, off, cnt)) return;
    int n0 = yn * BN;

    __shared__ __align__(16) u16 Als[BM * BK];
    __shared__ __align__(16) u16 Bls[BN * BK];

    int tid = threadIdx.x;
    int lane = tid & 63, wid = tid >> 6;
    int wr = wid >> 1, wc = wid & 1;

    f32x4 acc[4][4];
#pragma unroll
    for (int i = 0; i < 4; i++)
#pragma unroll
        for (int j = 0; j < 4; j++) acc[i][j] = (f32x4)(0.f);

    const u16* aSrc[8];
    const u16* bSrc[8];
#pragma unroll
    for (int i = 0; i < 8; i++) {
        int c = i * 256 + tid;
        int row = c >> 4;
        int g = (c & 15) ^ (row & 7);
        int lrow = m0 + row;
        int grow = off + ((lrow < cnt) ? lrow : (cnt - 1));
        aSrc[i] = H + (size_t)grow * FF + g * 8;
        bSrc[i] = w2t + (size_t)e * DIM * FF + (size_t)(n0 + row) * FF + g * 8;
    }
    int ldsOff = wid * 512;

    constexpr int NKT = FF / BK;  // 32
#pragma unroll 2
    for (int kt = 0; kt < NKT; ++kt) {
        STAGE(kt);
        __syncthreads();
        COMPUTE();
        __syncthreads();
    }

#pragma unroll
    for (int mi = 0; mi < 4; mi++) {
#pragma unroll
        for (int r = 0; r < 4; r++) {
            int lrow = m0 + wr * 64 + mi * 16 + ((lane >> 4) << 2) + r;
            if (lrow >= cnt) continue;
            int rv = rows[off + lrow];
            float wgt = roww[off + lrow];
            float* op = out + (size_t)(rv >> 1) * DIM + n0 + wc * 64;
#pragma unroll
            for (int nj = 0; nj < 4; nj++)
                atomicAdd(&op[nj * 16 + (lane & 15)], wgt * acc[mi][nj][r]);
        }
    }
}

extern "C" void kernel_launch(void* const* d_in, const int* in_sizes, int n_in,
                              void* d_out, int out_size, void* d_ws, size_t ws_size,
                              hipStream_t stream) {
    const float* x  = (const float*)d_in[0];
    const float* Wr = (const float*)d_in[1];
    const float* W1 = (const float*)d_in[2];
    const float* W2 = (const float*)d_in[3];
    float* out = (float*)d_out;

    char* w = (char*)d_ws;
    size_t o = 0;
    auto carve = [&](size_t bytes) -> void* {
        void* p = w + o;
        o = (o + bytes + 255) & ~(size_t)255;
        return p;
    };
    int*   counts = (int*)carve(2 * NE * 4);   // counts[8] + cur0[8], one memset
    int*   cur0   = counts + NE;
    int*   topi   = (int*)carve((size_t)NT * 2 * 4);
    float* topw   = (float*)carve((size_t)NT * 2 * 4);
    int*   rows   = (int*)carve((size_t)NT * 2 * 4);
    float* roww   = (float*)carve((size_t)NT * 2 * 4);
    u16*   xbf    = (u16*)carve((size_t)NT * DIM * 2);
    u16*   w1t    = (u16*)carve((size_t)NE * DIM * FF * 2);
    u16*   w2t    = (u16*)carve((size_t)NE * DIM * FF * 2);
    u16*   Hbuf   = (u16*)carve((size_t)NT * 2 * FF * 2);
    (void)ws_size; (void)in_sizes; (void)n_in; (void)out_size;

    hipMemsetAsync(counts, 0, 2 * NE * 4, stream);
    hipMemsetAsync(d_out, 0, (size_t)NT * DIM * 4, stream);

    k_router<<<NT / 4, 256, 0, stream>>>(x, Wr, topi, topw, counts, xbf);
    k_build<<<NT / 256, 256, 0, stream>>>(topi, topw, counts, cur0, rows, roww);
    k_tcvt2<<<16384, 256, 0, stream>>>(W1, W2, w1t, w2t);
    k_gemm1<<<G1X, 256, 0, stream>>>(xbf, w1t, rows, counts, Hbuf);
    k_gemm2<<<G2X, 256, 0, stream>>>(Hbuf, w2t, rows, roww, counts, out);
}

// Round 15
// 710.692 us; speedup vs baseline: 1.1134x; 1.1134x over previous
//
#include <hip/hip_runtime.h>
#include <hip/hip_bf16.h>

using u16 = unsigned short;
using u32 = unsigned int;

typedef __bf16 bf16x8 __attribute__((ext_vector_type(8)));
typedef float f32x4 __attribute__((ext_vector_type(4)));
typedef float f32x4v __attribute__((ext_vector_type(4)));
typedef unsigned short u16x8 __attribute__((ext_vector_type(8)));

constexpr int NT  = 8192;   // B*T tokens
constexpr int DIM = 1024;
constexpr int FF  = 4096;
constexpr int NE  = 8;      // experts

constexpr int BM = 128, BN = 128, BK = 64;
constexpr int MAXMB = 136;              // max m-blocks: NT*2/BM + NE  (= 17*8)
constexpr int G1X = MAXMB * (FF / BN);  // 136*32 = 4352  (%8==0)
constexpr int G2X = MAXMB * (DIM / BN); // 136*8  = 1088  (%8==0; = 34*32)

__device__ inline u16 f2bf(float f) {
    u32 u = __float_as_uint(f);
    u32 r = (u + 0x7fffu + ((u >> 16) & 1u)) >> 16;
    return (u16)r;
}

// direct global->LDS, 16B per lane, wave-uniform LDS base + lane*16
__device__ inline void gload16(const void* g, void* l) {
    __builtin_amdgcn_global_load_lds(
        (const __attribute__((address_space(1))) void*)g,
        (__attribute__((address_space(3))) void*)l, 16, 0, 0);
}

// derive (e, m0, off, cnt) for m-block xm from counts[8] (8-step scalar scan)
__device__ inline bool derive_mb(const int* __restrict__ counts, int xm,
                                 int& e, int& m0, int& off, int& cnt) {
    int cum = 0, ofs = 0;
    e = -1;
#pragma unroll
    for (int ee = 0; ee < NE; ee++) {
        int c = counts[ee];
        int nb = (c + BM - 1) >> 7;
        if (e < 0) {
            if (xm < cum + nb) { e = ee; m0 = (xm - cum) * BM; cnt = c; off = ofs; }
            else ofs += c;
        }
        cum += nb;
    }
    return e >= 0;
}

// ---------------- router: logits -> top2 -> softmax weights (+ x -> bf16) ----------------
__global__ __launch_bounds__(256) void k_router(const float* __restrict__ x,
                                                const float* __restrict__ Wr,
                                                int* __restrict__ topi,
                                                float* __restrict__ topw,
                                                int* __restrict__ counts,
                                                u16* __restrict__ xbf) {
    int w = threadIdx.x >> 6, lane = threadIdx.x & 63;
    int t = blockIdx.x * 4 + w;
    const float* xt = x + (size_t)t * DIM;
    u16* xo = xbf + (size_t)t * DIM;
    float acc[NE];
#pragma unroll
    for (int e = 0; e < NE; e++) acc[e] = 0.f;
    for (int i = 0; i < DIM / 64; i++) {
        int d = i * 64 + lane;
        float xv = xt[d];
        xo[d] = f2bf(xv);                       // fused x -> bf16 (coalesced)
#pragma unroll
        for (int e = 0; e < NE; e++) acc[e] += xv * Wr[e * DIM + d];
    }
#pragma unroll
    for (int e = 0; e < NE; e++) {
#pragma unroll
        for (int off = 32; off >= 1; off >>= 1) acc[e] += __shfl_xor(acc[e], off, 64);
    }
    if (lane == 0) {
        int b0 = 0; float v0 = acc[0];
        for (int e = 1; e < NE; e++) if (acc[e] > v0) { v0 = acc[e]; b0 = e; }
        int b1 = -1; float v1 = -INFINITY;
        for (int e = 0; e < NE; e++) if (e != b0 && acc[e] > v1) { v1 = acc[e]; b1 = e; }
        float e1 = __expf(v1 - v0);
        float w0 = 1.f / (1.f + e1);
        topi[t * 2] = b0; topi[t * 2 + 1] = b1;
        topw[t * 2] = w0; topw[t * 2 + 1] = 1.f - w0;
        atomicAdd(&counts[b0], 1);
        atomicAdd(&counts[b1], 1);
    }
}

// ---------------- build per-expert row lists (ballot-aggregated atomics) ----------------
__global__ __launch_bounds__(256) void k_build(const int* __restrict__ topi,
                                               const float* __restrict__ topw,
                                               const int* __restrict__ counts,
                                               int* __restrict__ cur0,
                                               int* __restrict__ rows,
                                               float* __restrict__ roww) {
    int t = blockIdx.x * 256 + threadIdx.x;
    int lane = threadIdx.x & 63;
    int offsL[NE]; int s = 0;
#pragma unroll
    for (int e = 0; e < NE; e++) { offsL[e] = s; s += counts[e]; }
#pragma unroll
    for (int sl = 0; sl < 2; sl++) {
        int e = topi[t * 2 + sl];
#pragma unroll
        for (int ee = 0; ee < NE; ee++) {
            unsigned long long mask = __ballot(e == ee);
            if (e == ee) {
                int leader = __ffsll((long long)mask) - 1;
                int cntw = __popcll(mask);
                int base = 0;
                if (lane == leader) base = atomicAdd(&cur0[ee], cntw);
                base = __shfl(base, leader, 64);
                int rank = __popcll(mask & ((1ULL << lane) - 1ULL));
                int p = offsL[ee] + base + rank;
                rows[p] = t * 2 + sl;
                roww[p] = topw[t * 2 + sl];
            }
        }
    }
}

// ---------------- fused transpose+convert for W1 and W2 ----------------
__global__ __launch_bounds__(256) void k_tcvt2(const float* __restrict__ W1,
                                               const float* __restrict__ W2,
                                               u16* __restrict__ w1t,
                                               u16* __restrict__ w2t) {
    __shared__ float tile[64][65];
    int b = blockIdx.x;
    const float* pin; u16* pout; int R, C, cx, cy;
    if (b < 8192) {
        int e = b >> 10, r = b & 1023;
        cx = r & 63; cy = r >> 6;               // (FF/64)=64 x (DIM/64)=16
        R = DIM; C = FF;
        pin = W1 + (size_t)e * DIM * FF;
        pout = w1t + (size_t)e * DIM * FF;
    } else {
        int bb = b - 8192;
        int e = bb >> 10, r = bb & 1023;
        cx = r & 15; cy = r >> 4;               // (DIM/64)=16 x (FF/64)=64
        R = FF; C = DIM;
        pin = W2 + (size_t)e * DIM * FF;
        pout = w2t + (size_t)e * DIM * FF;
    }
    int c0 = cx * 64, r0 = cy * 64;
    int t = threadIdx.x;
    int lc = (t & 15) * 4, lr = t >> 4;
#pragma unroll
    for (int i = 0; i < 4; i++) {
        int r = lr + i * 16;
        f32x4v v = *reinterpret_cast<const f32x4v*>(&pin[(size_t)(r0 + r) * C + c0 + lc]);
        tile[r][lc] = v[0]; tile[r][lc + 1] = v[1];
        tile[r][lc + 2] = v[2]; tile[r][lc + 3] = v[3];
    }
    __syncthreads();
    int oc = (t & 7) * 8;
    int orow = t >> 3;
#pragma unroll
    for (int i = 0; i < 2; i++) {
        int cc = orow + i * 32;
        u16x8 o;
#pragma unroll
        for (int j = 0; j < 8; j++) o[j] = f2bf(tile[oc + j][cc]);
        *reinterpret_cast<u16x8*>(&pout[(size_t)(c0 + cc) * R + r0 + oc]) = o;
    }
}

// ======== m97-style single-buffer 128x128x64 GEMM machinery (R13 proven best) ========
// LDS swizzle (both-sides): stage chunk c: row=c>>3, src col-chunk g=(c&7)^(row&7),
// linear LDS dest; frag read slot s=(kk*4+(lane>>4))^(row&7). Conflict-free at BK=64
// (verified 0; R14 showed BK=128 breaks this: 1.7e7 conflicts -> reverted).
// launch_bounds(256,2): R11/R13 measured 72 VGPR / ~26% occ / MfmaUtil 27% -- best.

#define STAGE(kt) do { \
    _Pragma("unroll") for (int i_ = 0; i_ < 4; i_++) \
        gload16(aSrc[i_] + (kt) * BK, &Als[i_ * 2048 + ldsOff]); \
    _Pragma("unroll") for (int i_ = 0; i_ < 4; i_++) \
        gload16(bSrc[i_] + (kt) * BK, &Bls[i_ * 2048 + ldsOff]); \
} while (0)

#define COMPUTE() do { \
    bf16x8 af[2][4], bfr[2][4]; \
    _Pragma("unroll") for (int kk = 0; kk < 2; kk++) { \
        _Pragma("unroll") for (int mi = 0; mi < 4; mi++) { \
            int row = wr * 64 + mi * 16 + (lane & 15); \
            int s = (kk * 4 + (lane >> 4)) ^ (row & 7); \
            af[kk][mi] = *reinterpret_cast<const bf16x8*>(&Als[row * BK + s * 8]); } \
        _Pragma("unroll") for (int nj = 0; nj < 4; nj++) { \
            int row = wc * 64 + nj * 16 + (lane & 15); \
            int s = (kk * 4 + (lane >> 4)) ^ (row & 7); \
            bfr[kk][nj] = *reinterpret_cast<const bf16x8*>(&Bls[row * BK + s * 8]); } } \
    _Pragma("unroll") for (int kk = 0; kk < 2; kk++) \
    _Pragma("unroll") for (int mi = 0; mi < 4; mi++) \
    _Pragma("unroll") for (int nj = 0; nj < 4; nj++) \
        acc[mi][nj] = __builtin_amdgcn_mfma_f32_16x16x32_bf16(af[kk][mi], bfr[kk][nj], acc[mi][nj], 0, 0, 0); \
} while (0)

// ---------------- GEMM1: H = gelu(x @ W1[e]) ----------------
__global__ __launch_bounds__(256, 2) void k_gemm1(const u16* __restrict__ xbf,
                                                  const u16* __restrict__ w1t, // [E][FF][DIM]
                                                  const int* __restrict__ rows,
                                                  const int* __restrict__ counts,
                                                  u16* __restrict__ H) {
    int l = ((int)blockIdx.x & 7) * (G1X >> 3) + ((int)blockIdx.x >> 3);
    // grouped-snake: groups of 8 token-panels (2 MB, L2-resident) sweep all 32
    // weight panels; weights stream once via L3 instead of 8x64 MB thrash.
    int gid = l >> 8;                 // l / 256  (17 groups)
    int xm = gid * 8 + ((l & 255) & 7);
    int yn = (l & 255) >> 3;
    int e, m0, off, cnt;
    if (!derive_mb(counts, xm, e, m0, off, cnt)) return;
    int n0 = yn * BN;

    __shared__ __align__(16) u16 Als[BM * BK];   // 16 KB
    __shared__ __align__(16) u16 Bls[BN * BK];   // 16 KB

    int tid = threadIdx.x;
    int lane = tid & 63, wid = tid >> 6;
    int wr = wid >> 1, wc = wid & 1;

    f32x4 acc[4][4];
#pragma unroll
    for (int i = 0; i < 4; i++)
#pragma unroll
        for (int j = 0; j < 4; j++) acc[i][j] = (f32x4)(0.f);

    const u16* aSrc[4];
    const u16* bSrc[4];
#pragma unroll
    for (int i = 0; i < 4; i++) {
        int row = i * 32 + (tid >> 3);
        int g = (tid & 7) ^ (row & 7);
        int lrow = m0 + row;
        int tok = (lrow < cnt) ? (rows[off + lrow] >> 1) : 0;
        aSrc[i] = xbf + (size_t)tok * DIM + g * 8;
        bSrc[i] = w1t + (size_t)e * FF * DIM + (size_t)(n0 + row) * DIM + g * 8;
    }
    int ldsOff = wid * 512;   // elems; + i*2048 per chunk

    constexpr int NKT = DIM / BK;  // 16
#pragma unroll 2
    for (int kt = 0; kt < NKT; ++kt) {
        STAGE(kt);
        __syncthreads();   // drains vmcnt; tile ready
        COMPUTE();
        __syncthreads();   // reads done; safe to restage
    }

    // epilogue: exact GELU -> bf16 H
#pragma unroll
    for (int mi = 0; mi < 4; mi++) {
#pragma unroll
        for (int r = 0; r < 4; r++) {
            int lrow = m0 + wr * 64 + mi * 16 + ((lane >> 4) << 2) + r;
            if (lrow >= cnt) continue;
            u16* hp = H + (size_t)(off + lrow) * FF + n0 + wc * 64;
#pragma unroll
            for (int nj = 0; nj < 4; nj++) {
                float v = acc[mi][nj][r];
                v = 0.5f * v * (1.f + erff(v * 0.70710678118f));
                hp[nj * 16 + (lane & 15)] = f2bf(v);
            }
        }
    }
}

// ---------------- GEMM2: out[token] += w * (H[row] @ W2[e]) ----------------
__global__ __launch_bounds__(256, 2) void k_gemm2(const u16* __restrict__ H,
                                                  const u16* __restrict__ w2t, // [E][DIM][FF]
                                                  const int* __restrict__ rows,
                                                  const float* __restrict__ roww,
                                                  const int* __restrict__ counts,
                                                  float* __restrict__ out) {
    int l = ((int)blockIdx.x & 7) * (G2X >> 3) + ((int)blockIdx.x >> 3);
    // grouped-snake (group=4): 4 H-panels (4x128x4096x2B = 4 MB, L2-resident)
    // sweep all 8 w2 panels; w2 streams once via L3 instead of 8x64 MB thrash.
    int gid = l >> 5;                 // l / 32  (34 groups)
    int xm = gid * 4 + ((l & 31) & 3);
    int yn = (l & 31) >> 2;
    int e, m0, off, cnt;
    if (!derive_mb(counts, xm, e, m0, off, cnt)) return;
    int n0 = yn * BN;

    __shared__ __align__(16) u16 Als[BM * BK];
    __shared__ __align__(16) u16 Bls[BN * BK];

    int tid = threadIdx.x;
    int lane = tid & 63, wid = tid >> 6;
    int wr = wid >> 1, wc = wid & 1;

    f32x4 acc[4][4];
#pragma unroll
    for (int i = 0; i < 4; i++)
#pragma unroll
        for (int j = 0; j < 4; j++) acc[i][j] = (f32x4)(0.f);

    const u16* aSrc[4];
    const u16* bSrc[4];
#pragma unroll
    for (int i = 0; i < 4; i++) {
        int row = i * 32 + (tid >> 3);
        int g = (tid & 7) ^ (row & 7);
        int lrow = m0 + row;
        int grow = off + ((lrow < cnt) ? lrow : (cnt - 1));
        aSrc[i] = H + (size_t)grow * FF + g * 8;
        bSrc[i] = w2t + (size_t)e * DIM * FF + (size_t)(n0 + row) * FF + g * 8;
    }
    int ldsOff = wid * 512;

    constexpr int NKT = FF / BK;  // 64
#pragma unroll 2
    for (int kt = 0; kt < NKT; ++kt) {
        STAGE(kt);
        __syncthreads();
        COMPUTE();
        __syncthreads();
    }

#pragma unroll
    for (int mi = 0; mi < 4; mi++) {
#pragma unroll
        for (int r = 0; r < 4; r++) {
            int lrow = m0 + wr * 64 + mi * 16 + ((lane >> 4) << 2) + r;
            if (lrow >= cnt) continue;
            int rv = rows[off + lrow];
            float wgt = roww[off + lrow];
            float* op = out + (size_t)(rv >> 1) * DIM + n0 + wc * 64;
#pragma unroll
            for (int nj = 0; nj < 4; nj++)
                atomicAdd(&op[nj * 16 + (lane & 15)], wgt * acc[mi][nj][r]);
        }
    }
}

extern "C" void kernel_launch(void* const* d_in, const int* in_sizes, int n_in,
                              void* d_out, int out_size, void* d_ws, size_t ws_size,
                              hipStream_t stream) {
    const float* x  = (const float*)d_in[0];
    const float* Wr = (const float*)d_in[1];
    const float* W1 = (const float*)d_in[2];
    const float* W2 = (const float*)d_in[3];
    float* out = (float*)d_out;

    char* w = (char*)d_ws;
    size_t o = 0;
    auto carve = [&](size_t bytes) -> void* {
        void* p = w + o;
        o = (o + bytes + 255) & ~(size_t)255;
        return p;
    };
    int*   counts = (int*)carve(2 * NE * 4);   // counts[8] + cur0[8], one memset
    int*   cur0   = counts + NE;
    int*   topi   = (int*)carve((size_t)NT * 2 * 4);
    float* topw   = (float*)carve((size_t)NT * 2 * 4);
    int*   rows   = (int*)carve((size_t)NT * 2 * 4);
    float* roww   = (float*)carve((size_t)NT * 2 * 4);
    u16*   xbf    = (u16*)carve((size_t)NT * DIM * 2);
    u16*   w1t    = (u16*)carve((size_t)NE * DIM * FF * 2);
    u16*   w2t    = (u16*)carve((size_t)NE * DIM * FF * 2);
    u16*   Hbuf   = (u16*)carve((size_t)NT * 2 * FF * 2);
    (void)ws_size; (void)in_sizes; (void)n_in; (void)out_size;

    hipMemsetAsync(counts, 0, 2 * NE * 4, stream);
    hipMemsetAsync(d_out, 0, (size_t)NT * DIM * 4, stream);

    k_router<<<NT / 4, 256, 0, stream>>>(x, Wr, topi, topw, counts, xbf);
    k_build<<<NT / 256, 256, 0, stream>>>(topi, topw, counts, cur0, rows, roww);
    k_tcvt2<<<16384, 256, 0, stream>>>(W1, W2, w1t, w2t);
    k_gemm1<<<G1X, 256, 0, stream>>>(xbf, w1t, rows, counts, Hbuf);
    k_gemm2<<<G2X, 256, 0, stream>>>(Hbuf, w2t, rows, roww, counts, out);
}